// Round 2
// baseline (594.301 us; speedup 1.0000x reference)
//
#include <hip/hip_runtime.h>
#include <hip/hip_bf16.h>
#include <math.h>

// Problem: B=8, S=512, V=32000, M=32, PAD_ID=1
// logp[b,s] = logits[b,s,a[b,s]] - logsumexp_{m: mask[b,s,m]>0}(logits[b,s,mask[b,s,m]])
// out[b] = sum_s logp[b,s] * (a[b,s] != 1)
// Softmax Z cancels in p_a/base -> never touch the V dimension (524 MB -> ~17 MB).
//
// Single launch: 8 blocks (one per b) x 1024 threads (16 waves).
// Each wave owns 32 positions, processed 2 at a time:
//   lanes 0-31  -> even position, lanes 32-63 -> odd position.
// Butterfly shfl_xor with offsets 16..1 stays within each 32-lane half.
// mask/a indices are prefetched one pair ahead so the dependent gather's
// HBM latency overlaps the previous pair's reduce.

#define BB 8
#define SS 512
#define VV 32000
#define MM 32

__global__ __launch_bounds__(1024) void logp_fused_kernel(
    const float* __restrict__ logits,   // [B*S, V]
    const int*   __restrict__ a,        // [B*S]
    const int*   __restrict__ mask,     // [B*S, M]
    float*       __restrict__ out)      // [B]
{
    const int b    = blockIdx.x;            // 0..7
    const int wave = threadIdx.x >> 6;      // 0..15
    const int lane = threadIdx.x & 63;
    const int hl   = lane & 31;             // lane within half
    const int half = lane >> 5;             // 0: even pos, 1: odd pos

    // wave handles s in [wave*32, wave*32+32); iter i covers s0+2i+half
    const int pos_base = b * SS + wave * 32 + half;

    float acc = 0.0f;

    // prefetch iteration 0's indices
    int m_cur = mask[pos_base * MM + hl];
    int a_cur = a[pos_base];

    #pragma unroll
    for (int i = 0; i < 16; ++i) {
        const int pos = pos_base + 2 * i;
        const float* __restrict__ row = logits + (size_t)pos * VV;

        // gathers whose addresses were prefetched last iteration
        float x  = (m_cur > 0) ? row[m_cur] : -INFINITY;
        float la = row[a_cur];               // same addr across half -> broadcast
        const int a_hold = a_cur;

        // prefetch next pair's indices (overlaps with the reduce below)
        if (i < 15) {
            m_cur = mask[(pos + 2) * MM + hl];
            a_cur = a[pos + 2];
        }

        // segmented max over the 32-lane half
        float mx = x;
        #pragma unroll
        for (int off = 16; off; off >>= 1)
            mx = fmaxf(mx, __shfl_xor(mx, off, 64));

        // segmented sum of exp(x - mx)
        float e = (x == -INFINITY) ? 0.0f : expf(x - mx);
        #pragma unroll
        for (int off = 16; off; off >>= 1)
            e += __shfl_xor(e, off, 64);

        const float lse = mx + logf(e);
        if (hl == 0 && a_hold != 1) acc += la - lse;
    }

    // lane 0 holds even-pos sum, lane 32 holds odd-pos sum
    acc += __shfl_xor(acc, 32, 64);

    __shared__ float wsum[16];
    if (lane == 0) wsum[wave] = acc;
    __syncthreads();
    if (threadIdx.x == 0) {
        float s = 0.0f;
        #pragma unroll
        for (int w = 0; w < 16; ++w) s += wsum[w];
        out[b] = s;
    }
}

extern "C" void kernel_launch(void* const* d_in, const int* in_sizes, int n_in,
                              void* d_out, int out_size, void* d_ws, size_t ws_size,
                              hipStream_t stream) {
    const float* logits = (const float*)d_in[0];
    const int*   a      = (const int*)d_in[1];
    const int*   mask   = (const int*)d_in[2];
    float*       out    = (float*)d_out;

    logp_fused_kernel<<<BB, 1024, 0, stream>>>(logits, a, mask, out);
}